// Round 11
// baseline (194.632 us; speedup 1.0000x reference)
//
#include <hip/hip_runtime.h>
#include <hip/hip_bf16.h>

typedef __attribute__((ext_vector_type(8))) short short8;
typedef __attribute__((ext_vector_type(4))) float f32x4;
typedef __attribute__((ext_vector_type(16))) float f32x16;
typedef __attribute__((ext_vector_type(8))) unsigned short ushort8;
typedef __attribute__((ext_vector_type(2))) unsigned uint2v;

#define LOG2E 1.44269504088896340736f

__device__ __forceinline__ float fexp2(float x) {
#if __has_builtin(__builtin_amdgcn_exp2f)
  return __builtin_amdgcn_exp2f(x);
#else
  return exp2f(x);
#endif
}
__device__ __forceinline__ unsigned cvtpk(float lo, float hi) {
  unsigned r;
  asm("v_cvt_pk_bf16_f32 %0, %1, %2" : "=v"(r) : "v"(lo), "v"(hi));
  return r;
}
__device__ __forceinline__ void pswap32(unsigned &a, unsigned &b) {
#if __has_builtin(__builtin_amdgcn_permlane32_swap)
  uint2v r = __builtin_amdgcn_permlane32_swap(a, b, false, false);
  a = r[0]; b = r[1];
#else
  asm("v_permlane32_swap_b32 %0, %1" : "+v"(a), "+v"(b));
#endif
}
__device__ __forceinline__ void gload_lds16(const unsigned short* g, unsigned short* l) {
  __builtin_amdgcn_global_load_lds(
      (const __attribute__((address_space(1))) unsigned int*)g,
      (__attribute__((address_space(3))) unsigned int*)l, 16, 0, 0);
}

// ------- MFMA Q/K/V projection; writes Q,K as [bh][n][d], V as V^T [bh][d][n] --
__global__ __launch_bounds__(256) void proj_kernel(
    const float* __restrict__ x,
    const float* __restrict__ Wq, const float* __restrict__ Wk,
    const float* __restrict__ Wv,
    unsigned short* __restrict__ Qo, unsigned short* __restrict__ Ko,
    unsigned short* __restrict__ Vto)
{
  const int tid = threadIdx.x, lane = tid & 63, w = tid >> 6;
  const int r15 = lane & 15, G = lane >> 4;
  const int bh = blockIdx.x >> 4, nt = blockIdx.x & 15;
  const int b = bh >> 3, h = bh & 7;
  const int n0 = nt * 256 + w * 64;

  short8 xf[4][2];
  #pragma unroll
  for (int ct = 0; ct < 4; ++ct) {
    const int n = n0 + ct * 16 + r15;
    const float* xr = x + ((size_t)((b * 4096 + n) * 8 + h)) * 64;
    #pragma unroll
    for (int s = 0; s < 2; ++s) {
      const f32x4 f0 = *(const f32x4*)&xr[s * 32 + G * 8];
      const f32x4 f1 = *(const f32x4*)&xr[s * 32 + G * 8 + 4];
      union { unsigned u[4]; short8 s8; } uu;
      uu.u[0] = cvtpk(f0[0], f0[1]); uu.u[1] = cvtpk(f0[2], f0[3]);
      uu.u[2] = cvtpk(f1[0], f1[1]); uu.u[3] = cvtpk(f1[2], f1[3]);
      xf[ct][s] = uu.s8;
    }
  }

  const size_t obase = (size_t)bh * (4096 * 64);

  #pragma unroll
  for (int wi = 0; wi < 2; ++wi) {
    const float* W = wi ? Wk : Wq;
    unsigned short* O = wi ? Ko : Qo;
    const float sc = wi ? 1.0f : 0.125f * LOG2E;
    short8 wf[4][2];
    #pragma unroll
    for (int ft = 0; ft < 4; ++ft)
      #pragma unroll
      for (int s = 0; s < 2; ++s) {
        union { unsigned u[4]; short8 s8; } uu;
        #pragma unroll
        for (int jj = 0; jj < 4; ++jj) {
          const int k0 = s * 32 + G * 8 + jj * 2;
          uu.u[jj] = cvtpk(W[k0 * 64 + ft * 16 + r15] * sc,
                           W[(k0 + 1) * 64 + ft * 16 + r15] * sc);
        }
        wf[ft][s] = uu.s8;
      }
    f32x4 acc[4][4];
    #pragma unroll
    for (int ft = 0; ft < 4; ++ft)
      #pragma unroll
      for (int ct = 0; ct < 4; ++ct) acc[ft][ct] = (f32x4){0.f, 0.f, 0.f, 0.f};
    #pragma unroll
    for (int s = 0; s < 2; ++s)
      #pragma unroll
      for (int ft = 0; ft < 4; ++ft)
        #pragma unroll
        for (int ct = 0; ct < 4; ++ct)
          acc[ft][ct] = __builtin_amdgcn_mfma_f32_16x16x32_bf16(
              wf[ft][s], xf[ct][s], acc[ft][ct], 0, 0, 0);
    #pragma unroll
    for (int ft = 0; ft < 4; ++ft)
      #pragma unroll
      for (int ct = 0; ct < 4; ++ct) {
        uint2v pk;
        pk[0] = cvtpk(acc[ft][ct][0], acc[ft][ct][1]);
        pk[1] = cvtpk(acc[ft][ct][2], acc[ft][ct][3]);
        *(uint2v*)&O[obase + (size_t)(n0 + ct * 16 + r15) * 64 + ft * 16 + G * 4] = pk;
      }
  }

  {
    short8 wf[4][2];
    #pragma unroll
    for (int ft = 0; ft < 4; ++ft)
      #pragma unroll
      for (int s = 0; s < 2; ++s) {
        union { unsigned u[4]; short8 s8; } uu;
        #pragma unroll
        for (int jj = 0; jj < 4; ++jj) {
          const int k0 = s * 32 + G * 8 + jj * 2;
          uu.u[jj] = cvtpk(Wv[k0 * 64 + ft * 16 + r15], Wv[(k0 + 1) * 64 + ft * 16 + r15]);
        }
        wf[ft][s] = uu.s8;
      }
    f32x4 acc[4][4];
    #pragma unroll
    for (int ct = 0; ct < 4; ++ct)
      #pragma unroll
      for (int ft = 0; ft < 4; ++ft) acc[ct][ft] = (f32x4){0.f, 0.f, 0.f, 0.f};
    #pragma unroll
    for (int s = 0; s < 2; ++s)
      #pragma unroll
      for (int ct = 0; ct < 4; ++ct)
        #pragma unroll
        for (int ft = 0; ft < 4; ++ft)
          acc[ct][ft] = __builtin_amdgcn_mfma_f32_16x16x32_bf16(
              xf[ct][s], wf[ft][s], acc[ct][ft], 0, 0, 0);
    #pragma unroll
    for (int ct = 0; ct < 4; ++ct)
      #pragma unroll
      for (int ft = 0; ft < 4; ++ft) {
        uint2v pk;
        pk[0] = cvtpk(acc[ct][ft][0], acc[ct][ft][1]);
        pk[1] = cvtpk(acc[ct][ft][2], acc[ct][ft][3]);
        *(uint2v*)&Vto[obase + (size_t)(ft * 16 + r15) * 4096 + n0 + ct * 16 + G * 4] = pk;
      }
  }
}

// -------- flash attention, swapped QK^T via 32x32x16 MFMA, static-shift softmax
// grid 1024 = 32 bh x 32 qtiles(128). 4 waves x 32 q-rows. KV tile 64, dbuf LDS.
// R8/R10-proven sync skeleton: stage next tile at top, ONE __syncthreads per tile.
__global__ __launch_bounds__(256, 3) void attn_kernel(
    const unsigned short* __restrict__ Q, const unsigned short* __restrict__ K,
    const unsigned short* __restrict__ Vt, const float* __restrict__ Wo,
    const float* __restrict__ bo, float* __restrict__ out)
{
  // 32 KB: [ K dbuf 16KB | V dbuf 16KB ]; reused as 4 x 8KB fp32 O tiles at epilogue
  __shared__ __align__(16) unsigned short SM[16384];

  const int tid = threadIdx.x;
  const int lane = tid & 63, w = tid >> 6;
  const int l31 = lane & 31, hi = lane >> 5;
  const int r15 = lane & 15, G = lane >> 4;

  int bid = blockIdx.x;
  bid = (bid & 7) * 128 + (bid >> 3);          // XCD swizzle (1024 % 8 == 0)
  const int bh = bid >> 5, qt128 = bid & 31;

  const unsigned short* Qb = Q + (size_t)bh * (4096 * 64);
  const unsigned short* Kb = K + (size_t)bh * (4096 * 64);
  const unsigned short* Vb = Vt + (size_t)bh * (64 * 4096);
  const int q0w = qt128 * 128 + w * 32;

  // Q B-frags for 32x32x16: lane holds Q[q = q0w + l31][k = s*16 + hi*8 + j]
  short8 qf[4];
  {
    const unsigned short* qr = Qb + (size_t)(q0w + l31) * 64;
    #pragma unroll
    for (int s = 0; s < 4; ++s) qf[s] = *(const short8*)&qr[s * 16 + hi * 8];
  }

  short8 ones8;
  {
    union { unsigned short us[8]; short8 s8; } o;
    #pragma unroll
    for (int i = 0; i < 8; ++i) o.us[i] = 0x3F80;
    ones8 = o.s8;
  }

  f32x16 oacc[2];
  f32x16 lacc;
  #pragma unroll
  for (int r = 0; r < 16; ++r) { oacc[0][r] = 0.f; oacc[1][r] = 0.f; lacc[r] = 0.f; }

  // LDS read offsets (elements): row = l31 (+2048*kt32/dt), col8 = (s*2) ^ (hi ^ (row&7))
  int roffE[4];
  {
    const int m = hi ^ (l31 & 7);
    #pragma unroll
    for (int s = 0; s < 4; ++s) roffE[s] = l31 * 64 + ((s * 2) ^ m) * 8;
  }

  // staging: 8 segments of 512 elems per tile; wave w owns segs 2w, 2w+1.
  // unified swizzle (row&7)<<3 for both K and V^T (pre-swizzled global source).
  const int seg = w * 2;
  const int kr0 = seg * 8 + (lane >> 3), kr1 = kr0 + 8;
  const int c8 = (lane & 7) * 8;
  const int koff0 = kr0 * 64 + (c8 ^ ((kr0 & 7) << 3));
  const int koff1 = kr1 * 64 + (c8 ^ ((kr1 & 7) << 3));
  const int voff0 = kr0 * 4096 + (c8 ^ ((kr0 & 7) << 3));
  const int voff1 = kr1 * 4096 + (c8 ^ ((kr1 & 7) << 3));

  gload_lds16(Kb + koff0, &SM[seg * 512]);
  gload_lds16(Kb + koff1, &SM[(seg + 1) * 512]);
  gload_lds16(Vb + voff0, &SM[8192 + seg * 512]);
  gload_lds16(Vb + voff1, &SM[8192 + (seg + 1) * 512]);
  __syncthreads();

  auto TILE = [&](int bufc, int ktc) {
    if (ktc < 63) {
      const int ko = (ktc + 1) * 4096;
      const int vo = (ktc + 1) * 64;
      unsigned short* kd = &SM[(bufc ^ 1) * 4096];
      unsigned short* vd = &SM[8192 + (bufc ^ 1) * 4096];
      gload_lds16(Kb + ko + koff0, kd + seg * 512);
      gload_lds16(Kb + ko + koff1, kd + (seg + 1) * 512);
      gload_lds16(Vb + vo + voff0, vd + seg * 512);
      gload_lds16(Vb + vo + voff1, vd + (seg + 1) * 512);
    }

    const unsigned short* Kc = &SM[bufc * 4096];
    const unsigned short* Vc = &SM[8192 + bufc * 4096];

    // ---- per 32-key tile: S^T = K·Q (32x32), exp2, pack, 4 pswaps -> A-frags ----
    short8 pa[4];
    #pragma unroll
    for (int kt32 = 0; kt32 < 2; ++kt32) {
      f32x16 sk;
      #pragma unroll
      for (int r = 0; r < 16; ++r) sk[r] = 0.f;
      #pragma unroll
      for (int s = 0; s < 4; ++s) {
        const short8 kf = *(const short8*)&Kc[kt32 * 2048 + roffE[s]];
        sk = __builtin_amdgcn_mfma_f32_32x32x16_bf16(kf, qf[s], sk, 0, 0, 0);
      }
      // lane holds S[key=(r&3)+8*(r>>2)+4*hi (+32*kt32)][q=l31]
      float p[16];
      #pragma unroll
      for (int r = 0; r < 16; ++r) p[r] = fexp2(sk[r]);
      unsigned wv[8];
      #pragma unroll
      for (int i = 0; i < 8; ++i) wv[i] = cvtpk(p[2 * i], p[2 * i + 1]);
      // pairs chosen so outputs are directly A-frag regs (partner lane^32 = same q)
      pswap32(wv[0], wv[2]); pswap32(wv[1], wv[3]);
      pswap32(wv[4], wv[6]); pswap32(wv[5], wv[7]);
      union { unsigned u[4]; short8 s8; } f0, f1;
      f0.u[0] = wv[0]; f0.u[1] = wv[1]; f0.u[2] = wv[2]; f0.u[3] = wv[3];
      f1.u[0] = wv[4]; f1.u[1] = wv[5]; f1.u[2] = wv[6]; f1.u[3] = wv[7];
      pa[2 * kt32 + 0] = f0.s8;
      pa[2 * kt32 + 1] = f1.s8;
    }

    // ---- lsum on matrix pipe: lacc += P · ones (rows align with O rows) ----
    #pragma unroll
    for (int s = 0; s < 4; ++s)
      lacc = __builtin_amdgcn_mfma_f32_32x32x16_bf16(pa[s], ones8, lacc, 0, 0, 0);

    // ---- O += P V ----
    #pragma unroll
    for (int dt = 0; dt < 2; ++dt)
      #pragma unroll
      for (int s = 0; s < 4; ++s) {
        const short8 vb = *(const short8*)&Vc[dt * 2048 + roffE[s]];
        oacc[dt] = __builtin_amdgcn_mfma_f32_32x32x16_bf16(pa[s], vb, oacc[dt], 0, 0, 0);
      }
    __syncthreads();
  };

  for (int kt = 0; kt < 64; kt += 2) {
    TILE(0, kt);
    TILE(1, kt + 1);
  }

  // ---- fused epilogue: normalize -> LDS fp32 tile -> O·Wo + bo -> out ----
  // oacc/lacc rows share q = (r&3)+8*(r>>2)+4*hi; no shuffles needed.
  float* Ol = (float*)&SM[0] + w * 2048;   // 32 q x 64 d, XOR-swizzled cols
  #pragma unroll
  for (int dt = 0; dt < 2; ++dt)
    #pragma unroll
    for (int r = 0; r < 16; ++r) {
      const int q = (r & 3) + 8 * (r >> 2) + 4 * hi;
      const int d = dt * 32 + l31;
      Ol[q * 64 + (d ^ ((q & 7) << 3))] = oacc[dt][r] * __builtin_amdgcn_rcpf(lacc[r]);
    }

  // Wo B-frags (bf16, 16x16x32 epilogue) + bias
  short8 wof[4][2];
  #pragma unroll
  for (int nt = 0; nt < 4; ++nt)
    #pragma unroll
    for (int st = 0; st < 2; ++st) {
      union { unsigned u[4]; short8 s8; } uu;
      #pragma unroll
      for (int jj = 0; jj < 4; ++jj) {
        const int k0 = st * 32 + G * 8 + jj * 2;
        uu.u[jj] = cvtpk(Wo[k0 * 64 + nt * 16 + r15], Wo[(k0 + 1) * 64 + nt * 16 + r15]);
      }
      wof[nt][st] = uu.s8;
    }
  float bov[4];
  #pragma unroll
  for (int nt = 0; nt < 4; ++nt) bov[nt] = bo[nt * 16 + r15];

  const int b = bh >> 3, hh = bh & 7;
  #pragma unroll
  for (int qt2 = 0; qt2 < 2; ++qt2) {
    short8 af[2];
    #pragma unroll
    for (int st = 0; st < 2; ++st) {
      const int row = qt2 * 16 + r15;
      const int c = (st * 32 + G * 8) ^ ((row & 7) << 3);
      const f32x4 f0 = *(const f32x4*)&Ol[row * 64 + c];
      const f32x4 f1 = *(const f32x4*)&Ol[row * 64 + c + 4];
      union { unsigned u[4]; short8 s8; } uu;
      uu.u[0] = cvtpk(f0[0], f0[1]); uu.u[1] = cvtpk(f0[2], f0[3]);
      uu.u[2] = cvtpk(f1[0], f1[1]); uu.u[3] = cvtpk(f1[2], f1[3]);
      af[st] = uu.s8;
    }
    #pragma unroll
    for (int nt = 0; nt < 4; ++nt) {
      f32x4 dacc = (f32x4){bov[nt], bov[nt], bov[nt], bov[nt]};
      dacc = __builtin_amdgcn_mfma_f32_16x16x32_bf16(af[0], wof[nt][0], dacc, 0, 0, 0);
      dacc = __builtin_amdgcn_mfma_f32_16x16x32_bf16(af[1], wof[nt][1], dacc, 0, 0, 0);
      #pragma unroll
      for (int g = 0; g < 4; ++g) {
        const int nq = q0w + qt2 * 16 + G * 4 + g;
        out[((size_t)(b * 4096 + nq) * 8 + hh) * 64 + nt * 16 + r15] = dacc[g];
      }
    }
  }
}

extern "C" void kernel_launch(void* const* d_in, const int* in_sizes, int n_in,
                              void* d_out, int out_size, void* d_ws, size_t ws_size,
                              hipStream_t stream) {
  const float* x  = (const float*)d_in[0];
  const float* Wq = (const float*)d_in[1];
  const float* Wk = (const float*)d_in[2];
  const float* Wv = (const float*)d_in[3];
  const float* Wo = (const float*)d_in[4];
  const float* bo = (const float*)d_in[5];

  const size_t NE = 8388608;
  unsigned short* Qw  = (unsigned short*)d_ws;
  unsigned short* Kw  = Qw + NE;
  unsigned short* Vtw = Kw + NE;

  proj_kernel<<<512, 256, 0, stream>>>(x, Wq, Wk, Wv, Qw, Kw, Vtw);
  attn_kernel<<<1024, 256, 0, stream>>>(Qw, Kw, Vtw, Wo, bo, (float*)d_out);
}

// Round 12
// 172.615 us; speedup vs baseline: 1.1276x; 1.1276x over previous
//
#include <hip/hip_runtime.h>
#include <hip/hip_bf16.h>

typedef __attribute__((ext_vector_type(8))) short short8;
typedef __attribute__((ext_vector_type(4))) float f32x4;
typedef __attribute__((ext_vector_type(8))) unsigned short ushort8;
typedef __attribute__((ext_vector_type(2))) unsigned uint2v;

#define LOG2E 1.44269504088896340736f

__device__ __forceinline__ float fexp2(float x) {
#if __has_builtin(__builtin_amdgcn_exp2f)
  return __builtin_amdgcn_exp2f(x);
#else
  return exp2f(x);
#endif
}
__device__ __forceinline__ unsigned cvtpk(float lo, float hi) {
  unsigned r;
  asm("v_cvt_pk_bf16_f32 %0, %1, %2" : "=v"(r) : "v"(lo), "v"(hi));
  return r;
}
__device__ __forceinline__ void pswap32(unsigned &a, unsigned &b) {
#if __has_builtin(__builtin_amdgcn_permlane32_swap)
  uint2v r = __builtin_amdgcn_permlane32_swap(a, b, false, false);
  a = r[0]; b = r[1];
#else
  asm("v_permlane32_swap_b32 %0, %1" : "+v"(a), "+v"(b));
#endif
}
__device__ __forceinline__ void gload_lds16(const unsigned short* g, unsigned short* l) {
  __builtin_amdgcn_global_load_lds(
      (const __attribute__((address_space(1))) unsigned int*)g,
      (__attribute__((address_space(3))) unsigned int*)l, 16, 0, 0);
}
__device__ __forceinline__ int swzK(int r) {
  return ((r & 3) | (((r >> 3) & 1) << 2)) << 3;
}

// ------- MFMA Q/K/V projection; writes Q,K as [bh][n][d], V as V^T [bh][d][n] --
// grid 1024 = 32 bh x 32 ntiles(128 n). 4 waves; wave w owns 32 n (2 subtiles).
// Memory-bound: doubled grid (vs 512) -> 4 blocks/CU of TLP.
__global__ __launch_bounds__(256) void proj_kernel(
    const float* __restrict__ x,
    const float* __restrict__ Wq, const float* __restrict__ Wk,
    const float* __restrict__ Wv,
    unsigned short* __restrict__ Qo, unsigned short* __restrict__ Ko,
    unsigned short* __restrict__ Vto)
{
  const int tid = threadIdx.x, lane = tid & 63, w = tid >> 6;
  const int r15 = lane & 15, G = lane >> 4;
  const int bh = blockIdx.x >> 5, nt = blockIdx.x & 31;
  const int b = bh >> 3, h = bh & 7;
  const int n0 = nt * 128 + w * 32;

  short8 xf[2][2];
  #pragma unroll
  for (int ct = 0; ct < 2; ++ct) {
    const int n = n0 + ct * 16 + r15;
    const float* xr = x + ((size_t)((b * 4096 + n) * 8 + h)) * 64;
    #pragma unroll
    for (int s = 0; s < 2; ++s) {
      const f32x4 f0 = *(const f32x4*)&xr[s * 32 + G * 8];
      const f32x4 f1 = *(const f32x4*)&xr[s * 32 + G * 8 + 4];
      union { unsigned u[4]; short8 s8; } uu;
      uu.u[0] = cvtpk(f0[0], f0[1]); uu.u[1] = cvtpk(f0[2], f0[3]);
      uu.u[2] = cvtpk(f1[0], f1[1]); uu.u[3] = cvtpk(f1[2], f1[3]);
      xf[ct][s] = uu.s8;
    }
  }

  const size_t obase = (size_t)bh * (4096 * 64);

  #pragma unroll
  for (int wi = 0; wi < 2; ++wi) {
    const float* W = wi ? Wk : Wq;
    unsigned short* O = wi ? Ko : Qo;
    const float sc = wi ? 1.0f : 0.125f * LOG2E;
    short8 wf[4][2];
    #pragma unroll
    for (int ft = 0; ft < 4; ++ft)
      #pragma unroll
      for (int s = 0; s < 2; ++s) {
        union { unsigned u[4]; short8 s8; } uu;
        #pragma unroll
        for (int jj = 0; jj < 4; ++jj) {
          const int k0 = s * 32 + G * 8 + jj * 2;
          uu.u[jj] = cvtpk(W[k0 * 64 + ft * 16 + r15] * sc,
                           W[(k0 + 1) * 64 + ft * 16 + r15] * sc);
        }
        wf[ft][s] = uu.s8;
      }
    f32x4 acc[4][2];
    #pragma unroll
    for (int ft = 0; ft < 4; ++ft)
      #pragma unroll
      for (int ct = 0; ct < 2; ++ct) acc[ft][ct] = (f32x4){0.f, 0.f, 0.f, 0.f};
    #pragma unroll
    for (int s = 0; s < 2; ++s)
      #pragma unroll
      for (int ft = 0; ft < 4; ++ft)
        #pragma unroll
        for (int ct = 0; ct < 2; ++ct)
          acc[ft][ct] = __builtin_amdgcn_mfma_f32_16x16x32_bf16(
              wf[ft][s], xf[ct][s], acc[ft][ct], 0, 0, 0);
    #pragma unroll
    for (int ft = 0; ft < 4; ++ft)
      #pragma unroll
      for (int ct = 0; ct < 2; ++ct) {
        uint2v pk;
        pk[0] = cvtpk(acc[ft][ct][0], acc[ft][ct][1]);
        pk[1] = cvtpk(acc[ft][ct][2], acc[ft][ct][3]);
        *(uint2v*)&O[obase + (size_t)(n0 + ct * 16 + r15) * 64 + ft * 16 + G * 4] = pk;
      }
  }

  {
    short8 wf[4][2];
    #pragma unroll
    for (int ft = 0; ft < 4; ++ft)
      #pragma unroll
      for (int s = 0; s < 2; ++s) {
        union { unsigned u[4]; short8 s8; } uu;
        #pragma unroll
        for (int jj = 0; jj < 4; ++jj) {
          const int k0 = s * 32 + G * 8 + jj * 2;
          uu.u[jj] = cvtpk(Wv[k0 * 64 + ft * 16 + r15], Wv[(k0 + 1) * 64 + ft * 16 + r15]);
        }
        wf[ft][s] = uu.s8;
      }
    f32x4 acc[2][4];
    #pragma unroll
    for (int ct = 0; ct < 2; ++ct)
      #pragma unroll
      for (int ft = 0; ft < 4; ++ft) acc[ct][ft] = (f32x4){0.f, 0.f, 0.f, 0.f};
    #pragma unroll
    for (int s = 0; s < 2; ++s)
      #pragma unroll
      for (int ct = 0; ct < 2; ++ct)
        #pragma unroll
        for (int ft = 0; ft < 4; ++ft)
          acc[ct][ft] = __builtin_amdgcn_mfma_f32_16x16x32_bf16(
              xf[ct][s], wf[ft][s], acc[ct][ft], 0, 0, 0);
    #pragma unroll
    for (int ct = 0; ct < 2; ++ct)
      #pragma unroll
      for (int ft = 0; ft < 4; ++ft) {
        uint2v pk;
        pk[0] = cvtpk(acc[ct][ft][0], acc[ct][ft][1]);
        pk[1] = cvtpk(acc[ct][ft][2], acc[ct][ft][3]);
        *(uint2v*)&Vto[obase + (size_t)(ft * 16 + r15) * 4096 + n0 + ct * 16 + G * 4] = pk;
      }
  }
}

// -------- flash attention, swapped QK^T, static-shift softmax, fused Wo -------
// grid 1024 = 32 bh x 32 qtiles(128). 4 waves x 32 q-rows. KV tile 64, dbuf LDS.
// R10 proven kernel: R8 skeleton + lsum via ones-MFMA + kt-loop unrolled x2.
__global__ __launch_bounds__(256, 4) void attn_kernel(
    const unsigned short* __restrict__ Q, const unsigned short* __restrict__ K,
    const unsigned short* __restrict__ Vt, const float* __restrict__ Wo,
    const float* __restrict__ bo, float* __restrict__ out)
{
  // 32 KB: [ K dbuf 16KB | V dbuf 16KB ]; reused as 4 x 8KB fp32 O tiles at epilogue
  __shared__ __align__(16) unsigned short SM[16384];

  const int tid = threadIdx.x;
  const int lane = tid & 63, w = tid >> 6;
  const int r15 = lane & 15, G = lane >> 4;

  int bid = blockIdx.x;
  bid = (bid & 7) * 128 + (bid >> 3);          // XCD swizzle (1024 % 8 == 0)
  const int bh = bid >> 5, qt128 = bid & 31;

  const unsigned short* Qb = Q + (size_t)bh * (4096 * 64);
  const unsigned short* Kb = K + (size_t)bh * (4096 * 64);
  const unsigned short* Vb = Vt + (size_t)bh * (64 * 4096);
  const int q0w = qt128 * 128 + w * 32;

  // Q fragments (B-operand layout): lane holds Q[q=lane&15][G*8+j]
  short8 qf[2][2];
  #pragma unroll
  for (int qt = 0; qt < 2; ++qt) {
    const unsigned short* qr = Qb + (size_t)(q0w + qt * 16 + r15) * 64;
    qf[qt][0] = *(const short8*)&qr[G * 8];
    qf[qt][1] = *(const short8*)&qr[32 + G * 8];
  }

  // ones B-fragment (bf16 1.0 everywhere): row-sum of P via the matrix pipe
  short8 ones8;
  {
    union { unsigned short us[8]; short8 s8; } o;
    #pragma unroll
    for (int i = 0; i < 8; ++i) o.us[i] = 0x3F80;
    ones8 = o.s8;
  }

  f32x4 oacc[2][4];
  #pragma unroll
  for (int qt = 0; qt < 2; ++qt)
    #pragma unroll
    for (int t = 0; t < 4; ++t) oacc[qt][t] = (f32x4){0.f, 0.f, 0.f, 0.f};
  f32x4 lacc[2];
  lacc[0] = (f32x4){0.f, 0.f, 0.f, 0.f};
  lacc[1] = (f32x4){0.f, 0.f, 0.f, 0.f};

  // hoisted LDS read offsets
  int kro[4][2], vro[4][2];
  {
    const int Rr = r15 >> 2, gg = r15 & 3;
    #pragma unroll
    for (int t = 0; t < 4; ++t) {
      const int row = gg + ((t & 1) << 2) + ((Rr & 1) << 3) + ((t >> 1) << 4) + ((Rr >> 1) << 5);
      const int sw = swzK(row);
      kro[t][0] = row * 64 + ((G * 8) ^ sw);
      kro[t][1] = row * 64 + ((32 + G * 8) ^ sw);
      const int vrow = t * 16 + r15;
      const int vs = (vrow & 7) << 3;
      vro[t][0] = vrow * 64 + ((G * 8) ^ vs);
      vro[t][1] = vrow * 64 + ((32 + G * 8) ^ vs);
    }
  }

  // staging: 8 segments of 512 elems per tile; wave w owns segs 2w, 2w+1.
  const int seg = w * 2;
  const int kr0 = seg * 8 + (lane >> 3), kr1 = kr0 + 8;
  const int c8 = (lane & 7) * 8;
  const int koff0 = kr0 * 64 + (c8 ^ swzK(kr0));
  const int koff1 = kr1 * 64 + (c8 ^ swzK(kr1));
  const int voff0 = kr0 * 4096 + (c8 ^ ((kr0 & 7) << 3));
  const int voff1 = kr1 * 4096 + (c8 ^ ((kr1 & 7) << 3));

  gload_lds16(Kb + koff0, &SM[seg * 512]);
  gload_lds16(Kb + koff1, &SM[(seg + 1) * 512]);
  gload_lds16(Vb + voff0, &SM[8192 + seg * 512]);
  gload_lds16(Vb + voff1, &SM[8192 + (seg + 1) * 512]);
  __syncthreads();

  // one tile iteration; bufc is a literal at every call site so the LDS base
  // folds into ds_read immediate offsets.
  auto TILE = [&](int bufc, int ktc) {
    if (ktc < 63) {
      const int ko = (ktc + 1) * 4096;
      const int vo = (ktc + 1) * 64;
      unsigned short* kd = &SM[(bufc ^ 1) * 4096];
      unsigned short* vd = &SM[8192 + (bufc ^ 1) * 4096];
      gload_lds16(Kb + ko + koff0, kd + seg * 512);
      gload_lds16(Kb + ko + koff1, kd + (seg + 1) * 512);
      gload_lds16(Vb + vo + voff0, vd + seg * 512);
      gload_lds16(Vb + vo + voff1, vd + (seg + 1) * 512);
    }

    const unsigned short* Kc = &SM[bufc * 4096];
    const unsigned short* Vc = &SM[8192 + bufc * 4096];

    // ---- S = K·Q (static shift: no max subtract; |S| <= ~12 in log2 space) ----
    f32x4 s[2][4];
    #pragma unroll
    for (int t = 0; t < 4; ++t) {
      const short8 kf0 = *(const short8*)&Kc[kro[t][0]];
      const short8 kf1 = *(const short8*)&Kc[kro[t][1]];
      f32x4 z0 = (f32x4){0.f, 0.f, 0.f, 0.f};
      f32x4 z1 = (f32x4){0.f, 0.f, 0.f, 0.f};
      z0 = __builtin_amdgcn_mfma_f32_16x16x32_bf16(kf0, qf[0][0], z0, 0, 0, 0);
      s[0][t] = __builtin_amdgcn_mfma_f32_16x16x32_bf16(kf1, qf[0][1], z0, 0, 0, 0);
      z1 = __builtin_amdgcn_mfma_f32_16x16x32_bf16(kf0, qf[1][0], z1, 0, 0, 0);
      s[1][t] = __builtin_amdgcn_mfma_f32_16x16x32_bf16(kf1, qf[1][1], z1, 0, 0, 0);
    }

    // ---- p = exp2(s); pack; permlane half-exchange (no scalar row-sums) ----
    short8 pa[2][2];
    #pragma unroll
    for (int qt = 0; qt < 2; ++qt) {
      float p[4][4];
      #pragma unroll
      for (int t = 0; t < 4; ++t)
        #pragma unroll
        for (int g = 0; g < 4; ++g) p[t][g] = fexp2(s[qt][t][g]);

      unsigned wA[4], wB[4];
      wA[0] = cvtpk(p[0][0], p[0][1]); wA[1] = cvtpk(p[0][2], p[0][3]);
      wA[2] = cvtpk(p[1][0], p[1][1]); wA[3] = cvtpk(p[1][2], p[1][3]);
      wB[0] = cvtpk(p[2][0], p[2][1]); wB[1] = cvtpk(p[2][2], p[2][3]);
      wB[2] = cvtpk(p[3][0], p[3][1]); wB[3] = cvtpk(p[3][2], p[3][3]);
      union { unsigned u[4]; short8 s8; } fa, fb;
      #pragma unroll
      for (int i = 0; i < 4; ++i) {
        pswap32(wA[i], wB[i]);
        fa.u[i] = wA[i];
        fb.u[i] = wB[i];
      }
      pa[qt][0] = fa.s8;
      pa[qt][1] = fb.s8;
    }

    // ---- lsum on the matrix pipe: lacc[qt] += P · ones ----
    lacc[0] = __builtin_amdgcn_mfma_f32_16x16x32_bf16(pa[0][0], ones8, lacc[0], 0, 0, 0);
    lacc[0] = __builtin_amdgcn_mfma_f32_16x16x32_bf16(pa[0][1], ones8, lacc[0], 0, 0, 0);
    lacc[1] = __builtin_amdgcn_mfma_f32_16x16x32_bf16(pa[1][0], ones8, lacc[1], 0, 0, 0);
    lacc[1] = __builtin_amdgcn_mfma_f32_16x16x32_bf16(pa[1][1], ones8, lacc[1], 0, 0, 0);

    // ---- O += P V ----
    #pragma unroll
    for (int t = 0; t < 4; ++t) {
      const short8 vb0 = *(const short8*)&Vc[vro[t][0]];
      const short8 vb1 = *(const short8*)&Vc[vro[t][1]];
      oacc[0][t] = __builtin_amdgcn_mfma_f32_16x16x32_bf16(pa[0][0], vb0, oacc[0][t], 0, 0, 0);
      oacc[0][t] = __builtin_amdgcn_mfma_f32_16x16x32_bf16(pa[0][1], vb1, oacc[0][t], 0, 0, 0);
      oacc[1][t] = __builtin_amdgcn_mfma_f32_16x16x32_bf16(pa[1][0], vb0, oacc[1][t], 0, 0, 0);
      oacc[1][t] = __builtin_amdgcn_mfma_f32_16x16x32_bf16(pa[1][1], vb1, oacc[1][t], 0, 0, 0);
    }
    __syncthreads();
  };

  for (int kt = 0; kt < 64; kt += 2) {
    TILE(0, kt);
    TILE(1, kt + 1);
  }

  // ---- fused epilogue: normalize -> LDS fp32 tile -> O·Wo + bo -> out ----
  // lacc[qt][g] already holds lsum for q = qt*16 + G*4 + g (no shuffles needed).
  float* Ol = (float*)&SM[0] + w * 2048;   // 32 q x 64 d, XOR-swizzled cols
  #pragma unroll
  for (int qt = 0; qt < 2; ++qt) {
    float li[4];
    #pragma unroll
    for (int g = 0; g < 4; ++g) li[g] = __builtin_amdgcn_rcpf(lacc[qt][g]);
    #pragma unroll
    for (int t = 0; t < 4; ++t)
      #pragma unroll
      for (int g = 0; g < 4; ++g) {
        const int q = qt * 16 + G * 4 + g;
        const int d = t * 16 + r15;
        Ol[q * 64 + (d ^ ((q & 7) << 3))] = oacc[qt][t][g] * li[g];
      }
  }

  // Wo B-frags (bf16) + bias, loaded at epilogue to keep main-loop VGPRs low
  short8 wof[4][2];
  #pragma unroll
  for (int nt = 0; nt < 4; ++nt)
    #pragma unroll
    for (int st = 0; st < 2; ++st) {
      union { unsigned u[4]; short8 s8; } uu;
      #pragma unroll
      for (int jj = 0; jj < 4; ++jj) {
        const int k0 = st * 32 + G * 8 + jj * 2;
        uu.u[jj] = cvtpk(Wo[k0 * 64 + nt * 16 + r15], Wo[(k0 + 1) * 64 + nt * 16 + r15]);
      }
      wof[nt][st] = uu.s8;
    }
  float bov[4];
  #pragma unroll
  for (int nt = 0; nt < 4; ++nt) bov[nt] = bo[nt * 16 + r15];

  const int b = bh >> 3, hh = bh & 7;
  #pragma unroll
  for (int qt2 = 0; qt2 < 2; ++qt2) {
    short8 af[2];
    #pragma unroll
    for (int st = 0; st < 2; ++st) {
      const int row = qt2 * 16 + r15;
      const int c = (st * 32 + G * 8) ^ ((row & 7) << 3);
      const f32x4 f0 = *(const f32x4*)&Ol[row * 64 + c];
      const f32x4 f1 = *(const f32x4*)&Ol[row * 64 + c + 4];
      union { unsigned u[4]; short8 s8; } uu;
      uu.u[0] = cvtpk(f0[0], f0[1]); uu.u[1] = cvtpk(f0[2], f0[3]);
      uu.u[2] = cvtpk(f1[0], f1[1]); uu.u[3] = cvtpk(f1[2], f1[3]);
      af[st] = uu.s8;
    }
    #pragma unroll
    for (int nt = 0; nt < 4; ++nt) {
      f32x4 dacc = (f32x4){bov[nt], bov[nt], bov[nt], bov[nt]};
      dacc = __builtin_amdgcn_mfma_f32_16x16x32_bf16(af[0], wof[nt][0], dacc, 0, 0, 0);
      dacc = __builtin_amdgcn_mfma_f32_16x16x32_bf16(af[1], wof[nt][1], dacc, 0, 0, 0);
      #pragma unroll
      for (int g = 0; g < 4; ++g) {
        const int nq = q0w + qt2 * 16 + G * 4 + g;
        out[((size_t)(b * 4096 + nq) * 8 + hh) * 64 + nt * 16 + r15] = dacc[g];
      }
    }
  }
}

extern "C" void kernel_launch(void* const* d_in, const int* in_sizes, int n_in,
                              void* d_out, int out_size, void* d_ws, size_t ws_size,
                              hipStream_t stream) {
  const float* x  = (const float*)d_in[0];
  const float* Wq = (const float*)d_in[1];
  const float* Wk = (const float*)d_in[2];
  const float* Wv = (const float*)d_in[3];
  const float* Wo = (const float*)d_in[4];
  const float* bo = (const float*)d_in[5];

  const size_t NE = 8388608;
  unsigned short* Qw  = (unsigned short*)d_ws;
  unsigned short* Kw  = Qw + NE;
  unsigned short* Vtw = Kw + NE;

  proj_kernel<<<1024, 256, 0, stream>>>(x, Wq, Wk, Wv, Qw, Kw, Vtw);
  attn_kernel<<<1024, 256, 0, stream>>>(Qw, Kw, Vtw, Wo, bo, (float*)d_out);
}